// Round 13
// baseline (105.649 us; speedup 1.0000x reference)
//
#include <hip/hip_runtime.h>
#include <math.h>

#ifndef __has_builtin
#define __has_builtin(x) 0
#endif

typedef __attribute__((ext_vector_type(8))) short bf16x8;
typedef __attribute__((ext_vector_type(4))) float f32x4;

__device__ __forceinline__ float fast_fract(float x) {
#if __has_builtin(__builtin_amdgcn_fractf)
    return __builtin_amdgcn_fractf(x);
#else
    return x - floorf(x);
#endif
}
__device__ __forceinline__ float fast_cos2pi(float x) {   // cos(2*pi*x), x in [0,1)
#if __has_builtin(__builtin_amdgcn_cosf)
    return __builtin_amdgcn_cosf(x);
#else
    return cosf(x * 6.28318530717958647692f);
#endif
}
__device__ __forceinline__ float fast_exp2(float x) {
#if __has_builtin(__builtin_amdgcn_exp2f)
    return __builtin_amdgcn_exp2f(x);
#else
    return exp2f(x);
#endif
}
__device__ __forceinline__ unsigned short f2bf(float f) { // RNE f32 -> bf16 bits
    unsigned u = __float_as_uint(f);
    return (unsigned short)((u + 0x7FFFu + ((u >> 16) & 1u)) >> 16);
}
__device__ __forceinline__ float bf2f(unsigned short b) {
    return __uint_as_float(((unsigned)b) << 16);
}
__device__ __forceinline__ unsigned packbf(float lo, float hi) { // 2 f32 -> u32 of 2 bf16
    return (unsigned)f2bf(lo) | ((unsigned)f2bf(hi) << 16);
}

constexpr int kN = 16384, kD = 8, kS = 8, kF = 1024, kR = 2048;
constexpr float kInv2Pi = 0.15915494309189535f;
constexpr float kLog2e  = 1.4426950408889634f;
// ws layout (tiles of 64 x uint4 = 1 KB):
//   [0,512)   prior B-frags (s,ft)
//   [512,640) update A1 z-frags (rt), rows = r
//   [640,704) update A2 cw^T frags (rb of 32 r), rows = s (8 valid)
constexpr int kWsPrior = 512, kWsZ = 128, kWsCw = 64;
constexpr int kWsTiles = kWsPrior + kWsZ + kWsCw;          // 704
constexpr size_t kWsNeed = (size_t)kWsTiles * 64 * 16;

// ===========================================================================
// PREP: build all MFMA fragments in d_ws (blocks 0..175) and ZERO out
// (blocks 176..207).  Fragment conventions verified (absmax 0.125, r6-r11).
// ===========================================================================
__global__ __launch_bounds__(256)
void prep_kernel(const float* __restrict__ omega, const float* __restrict__ phase,
                 const float* __restrict__ Z, const float* __restrict__ cw,
                 const float* __restrict__ lsp, uint4* __restrict__ ws,
                 float* __restrict__ out)
{
    if (blockIdx.x >= 176) {                       // zero out: 512 KB
        const int zid = (blockIdx.x - 176) * 256 + threadIdx.x;  // 0..8191
        float4* o4 = reinterpret_cast<float4*>(out);
        #pragma unroll
        for (int j = 0; j < 4; ++j)
            o4[zid * 4 + j] = (float4){0.f, 0.f, 0.f, 0.f};
        return;
    }
    const int job  = blockIdx.x * 256 + threadIdx.x;   // 0..45055
    const int lane = job & 63;
    const int tile = job >> 6;                          // 0..703
    const int g = lane >> 4, c = lane & 15;

    const float inv_ls = 1.0f / lsp[0];
    const float m_ang  = kInv2Pi * inv_ls;
    const float L      = kLog2e * inv_ls * inv_ls;

    unsigned short h[8];
    if (tile < kWsPrior) {
        const int s = tile >> 6, ft = tile & 63, f = ft * 16 + c;
        const float* om = omega + s * (kD * kF);
        const float* ph = phase + s * kF;
        #pragma unroll
        for (int j = 0; j < 8; ++j) {
            const int k = g * 8 + j;
            unsigned short v = 0;
            if (k < 16) {
                v = f2bf(om[(k & 7) * kF + f] * m_ang);
            } else if (k < 24) {
                const float w = om[(k - 16) * kF + f] * m_ang;
                v = f2bf(w - bf2f(f2bf(w)));
            } else if (k == 24) {
                v = f2bf(ph[f] * kInv2Pi);
            } else if (k == 25) {
                const float p = ph[f] * kInv2Pi;
                v = f2bf(p - bf2f(f2bf(p)));
            }
            h[j] = v;
        }
    } else if (tile < kWsPrior + kWsZ) {
        const int rt = tile - kWsPrior;
        const int r  = rt * 16 + c;                    // m = r (A-frag row)
        const float* zr = Z + r * kD;
        float zz = 0.f;
        #pragma unroll
        for (int d = 0; d < kD; ++d) zz = fmaf(zr[d], zr[d], zz);
        const float ztv = -0.5f * L * zz;
        #pragma unroll
        for (int j = 0; j < 8; ++j) {
            const int k = g * 8 + j;
            unsigned short v = 0;
            if (k < 8) {
                v = f2bf(L * zr[k]);
            } else if (k < 16) {
                v = f2bf(L * zr[k - 8]);
            } else if (k < 24) {
                const float w = L * zr[k - 16];
                v = f2bf(w - bf2f(f2bf(w)));
            } else if (k == 24) {
                v = f2bf(ztv);
            } else if (k == 25) {
                v = f2bf(ztv - bf2f(f2bf(ztv)));
            } else if (k < 28) {
                v = 0x3F80;                            // 1.0
            }
            h[j] = v;
        }
    } else {
        const int rb = tile - kWsPrior - kWsZ;         // 0..63
        const int r0 = rb * 32;
        #pragma unroll
        for (int j = 0; j < 8; ++j)
            h[j] = (c < 8) ? f2bf(cw[c * kR + r0 + g * 8 + j]) : (unsigned short)0;
    }
    uint4 w;
    w.x = (unsigned)h[0] | ((unsigned)h[1] << 16);
    w.y = (unsigned)h[2] | ((unsigned)h[3] << 16);
    w.z = (unsigned)h[4] | ((unsigned)h[5] << 16);
    w.w = (unsigned)h[6] | ((unsigned)h[7] << 16);
    ws[tile * 64 + lane] = w;
}

// Build x A/B fragment halves (g0/g2 = x_hi, g1 = x_lo).
__device__ __forceinline__ bf16x8 build_af_x(const float* __restrict__ X,
                                             int row, int g)
{
    float xv[kD];
    const float4 x0 = *reinterpret_cast<const float4*>(X + row * kD);
    const float4 x1 = *reinterpret_cast<const float4*>(X + row * kD + 4);
    xv[0]=x0.x; xv[1]=x0.y; xv[2]=x0.z; xv[3]=x0.w;
    xv[4]=x1.x; xv[5]=x1.y; xv[6]=x1.z; xv[7]=x1.w;
    bf16x8 af;
    if (g == 1) {
        #pragma unroll
        for (int j = 0; j < 8; ++j)
            af[j] = (short)f2bf(xv[j] - bf2f(f2bf(xv[j])));
    } else {
        #pragma unroll
        for (int j = 0; j < 8; ++j) af[j] = (short)f2bf(xv[j]);
    }
    return af;
}

// ===========================================================================
// FUSED MAIN v3h: r11 structure (passed, 101.58us) with HARDENED update
// transpose: volatile LDS accesses + compiler memory barrier between the
// in-wave ds_writes and ds_read (removes TBAA reordering hazard that is the
// prime suspect for r12's post-capture divergence).
// grid 1536 x 256thr (4 waves) = 6 blocks/CU fully resident.
//   bid%3 in {0,1} -> PRIOR (1024 blocks): ft-pairs, 4-MFMA batch,
//     16-deep trans batch, depth-1 prefetch.
//   bid%3 == 2 -> UPDATE (512 blocks): r7 proven body + prefetch.
// Both atomicAdd into zeroed out.
// ===========================================================================
__global__ __launch_bounds__(256, 6)
void fused_main(const float* __restrict__ X, const float* __restrict__ fw,
                const float* __restrict__ varp, const float* __restrict__ lsp,
                const uint4* __restrict__ wsP, const uint4* __restrict__ wsZ,
                const uint4* __restrict__ wsC, float* __restrict__ out)
{
    __shared__ unsigned b2raw[4][256];                 // update transpose, 4 KB
    __shared__ f32x4 red[2][2][2][16];                 // update reduce, 2 KB
    const int tid  = threadIdx.x;
    const int lane = tid & 63;
    const int w    = __builtin_amdgcn_readfirstlane(tid >> 6);
    const int c = lane & 15, g = lane >> 4;
    const int bid = blockIdx.x;
    const int btype = bid % 3;                         // 0,1 prior; 2 update

    if (btype != 2) {
        // ---------------- PRIOR ----------------
        const int pb = (bid / 3) * 2 + btype;          // 0..1023
        const int s  = pb & 7;
        const int ng = pb >> 3;                        // 0..127
        const int n0 = ng * 128 + w * 32;

        bf16x8 af0, af1;
        if (g == 3) {
            #pragma unroll
            for (int j = 0; j < 8; ++j) { af0[j] = 0; af1[j] = 0; }
            af0[0] = (short)0x3F80; af0[1] = (short)0x3F80;
            af1[0] = (short)0x3F80; af1[1] = (short)0x3F80;
        } else {
            af0 = build_af_x(X, n0 + c, g);
            af1 = build_af_x(X, n0 + 16 + c, g);
        }

        const float scale = sqrtf(2.0f * varp[0] / (float)kF);
        const uint4* bp  = wsP + s * 4096 + lane;
        const float* fwp = fw + s * kF + c;

        float acc[2][4];
        #pragma unroll
        for (int t = 0; t < 2; ++t)
            #pragma unroll
            for (int r = 0; r < 4; ++r) acc[t][r] = 0.f;

        uint4 bw0 = bp[0];
        uint4 bw1 = bp[64];
        float fv0 = fwp[0];
        float fv1 = fwp[16];

        for (int ft = 0; ft < 64; ft += 2) {
            const int nx = (ft + 2 < 64) ? ft + 2 : ft;
            const uint4 nbw0 = bp[nx * 64];            // depth-1 prefetch
            const uint4 nbw1 = bp[(nx + 1) * 64];
            const float nfv0 = fwp[nx * 16];
            const float nfv1 = fwp[(nx + 1) * 16];

            const bf16x8 bv0 = __builtin_bit_cast(bf16x8, bw0);
            const bf16x8 bv1 = __builtin_bit_cast(bf16x8, bw1);
            // 4 independent MFMA chains
            const f32x4 d00 = __builtin_amdgcn_mfma_f32_16x16x32_bf16(
                af0, bv0, (f32x4){0.f, 0.f, 0.f, 0.f}, 0, 0, 0);
            const f32x4 d01 = __builtin_amdgcn_mfma_f32_16x16x32_bf16(
                af1, bv0, (f32x4){0.f, 0.f, 0.f, 0.f}, 0, 0, 0);
            const f32x4 d10 = __builtin_amdgcn_mfma_f32_16x16x32_bf16(
                af0, bv1, (f32x4){0.f, 0.f, 0.f, 0.f}, 0, 0, 0);
            const f32x4 d11 = __builtin_amdgcn_mfma_f32_16x16x32_bf16(
                af1, bv1, (f32x4){0.f, 0.f, 0.f, 0.f}, 0, 0, 0);
            // 16-deep independent trans batch
            #pragma unroll
            for (int r = 0; r < 4; ++r) {
                acc[0][r] = fmaf(fv0, fast_cos2pi(fast_fract(d00[r])), acc[0][r]);
                acc[1][r] = fmaf(fv0, fast_cos2pi(fast_fract(d01[r])), acc[1][r]);
                acc[0][r] = fmaf(fv1, fast_cos2pi(fast_fract(d10[r])), acc[0][r]);
                acc[1][r] = fmaf(fv1, fast_cos2pi(fast_fract(d11[r])), acc[1][r]);
            }
            bw0 = nbw0; bw1 = nbw1; fv0 = nfv0; fv1 = nfv1;
        }

        #pragma unroll
        for (int m = 1; m <= 8; m <<= 1)
            #pragma unroll
            for (int t = 0; t < 2; ++t)
                #pragma unroll
                for (int r = 0; r < 4; ++r)
                    acc[t][r] += __shfl_xor(acc[t][r], m);

        if (c == 0) {
            #pragma unroll
            for (int t = 0; t < 2; ++t) {
                float* o = out + s * kN + n0 + t * 16 + g * 4;
                #pragma unroll
                for (int r = 0; r < 4; ++r) atomicAdd(o + r, scale * acc[t][r]);
            }
        }
    } else {
        // ---------------- UPDATE ----------------
        const int ub   = bid / 3;                      // 0..511
        const int tl   = w >> 1, half = w & 1;
        const int n0   = (ub * 2 + tl) * 16;

        const float inv_ls = 1.0f / lsp[0];
        const float L = kLog2e * inv_ls * inv_ls;

        bf16x8 bf1;
        {
            float xv[kD];
            const float4 x0 = *reinterpret_cast<const float4*>(X + (n0 + c) * kD);
            const float4 x1 = *reinterpret_cast<const float4*>(X + (n0 + c) * kD + 4);
            xv[0]=x0.x; xv[1]=x0.y; xv[2]=x0.z; xv[3]=x0.w;
            xv[4]=x1.x; xv[5]=x1.y; xv[6]=x1.z; xv[7]=x1.w;
            if (g == 3) {
                float xx = 0.f;
                #pragma unroll
                for (int d = 0; d < kD; ++d) xx = fmaf(xv[d], xv[d], xx);
                const float xt = -0.5f * L * xx;
                const unsigned short th = f2bf(xt);
                const unsigned short tlw = f2bf(xt - bf2f(th));
                #pragma unroll
                for (int j = 0; j < 8; ++j) bf1[j] = 0;
                bf1[0] = (short)0x3F80; bf1[1] = (short)0x3F80;
                bf1[2] = (short)th;     bf1[3] = (short)tlw;
            } else if (g == 1) {
                #pragma unroll
                for (int j = 0; j < 8; ++j)
                    bf1[j] = (short)f2bf(xv[j] - bf2f(f2bf(xv[j])));
            } else {
                #pragma unroll
                for (int j = 0; j < 8; ++j) bf1[j] = (short)f2bf(xv[j]);
            }
        }

        const int wbase = (g >> 1) * 64 + c * 4 + (g & 1) * 2;
        const int rbase = (g >> 1) * 128 + (g & 1) * 64 + c * 4;
        volatile unsigned* bb = &b2raw[w][0];          // volatile: no reorder

        const uint4* zp = wsZ + lane;
        const uint4* cp = wsC + lane;
        const int rb0 = half * 32;

        f32x4 acc = {0.f, 0.f, 0.f, 0.f};
        uint4 za = zp[(rb0 * 2) * 64];
        uint4 zb = zp[(rb0 * 2 + 1) * 64];
        uint4 cf = cp[rb0 * 64];

        for (int i = 0; i < 32; ++i) {
            const int rb = rb0 + i;
            const int rbn = (i < 31) ? rb + 1 : rb;
            const uint4 zan = zp[(rbn * 2) * 64];      // depth-1 prefetch
            const uint4 zbn = zp[(rbn * 2 + 1) * 64];
            const uint4 cfn = cp[rbn * 64];

            const f32x4 e0 = __builtin_amdgcn_mfma_f32_16x16x32_bf16(
                __builtin_bit_cast(bf16x8, za), bf1, (f32x4){0.f,0.f,0.f,0.f}, 0, 0, 0);
            const f32x4 e1 = __builtin_amdgcn_mfma_f32_16x16x32_bf16(
                __builtin_bit_cast(bf16x8, zb), bf1, (f32x4){0.f,0.f,0.f,0.f}, 0, 0, 0);

            float K0[4], K1[4];
            #pragma unroll
            for (int r = 0; r < 4; ++r) {
                K0[r] = fast_exp2(fminf(e0[r], 0.f));
                K1[r] = fast_exp2(fminf(e1[r], 0.f));
            }
            // Hardened in-wave transpose: volatile scalar writes, compiler
            // memory barrier, volatile reads -- program order guaranteed,
            // waitcnt inserted conservatively.  Same layout as r7-r11.
            bb[wbase]       = packbf(K0[0], K0[1]);
            bb[wbase + 1]   = packbf(K0[2], K0[3]);
            bb[wbase + 128] = packbf(K1[0], K1[1]);
            bb[wbase + 129] = packbf(K1[2], K1[3]);
            asm volatile("" ::: "memory");
            uint4 b2w;
            b2w.x = bb[rbase];
            b2w.y = bb[rbase + 1];
            b2w.z = bb[rbase + 2];
            b2w.w = bb[rbase + 3];

            acc = __builtin_amdgcn_mfma_f32_16x16x32_bf16(
                __builtin_bit_cast(bf16x8, cf), __builtin_bit_cast(bf16x8, b2w),
                acc, 0, 0, 0);

            za = zan; zb = zbn; cf = cfn;
        }

        if (g < 2) red[tl][half][g][c] = acc;
        __syncthreads();

        {
            const int tl2 = tid >> 7, s = (tid >> 4) & 7, n = tid & 15;
            const float sum = red[tl2][0][s >> 2][n][s & 3]
                            + red[tl2][1][s >> 2][n][s & 3];
            const int idx = s * kN + (ub * 2 + tl2) * 16 + n;
            atomicAdd(out + idx, varp[0] * sum);
        }
    }
}

// ===========================================================================
// Fallback (proven round-3 kernels) if ws_size is too small for fragments.
// ===========================================================================
__global__ __launch_bounds__(512, 8)
void prior_fb(const float* __restrict__ X, const float* __restrict__ omega,
              const float* __restrict__ phase, const float* __restrict__ fw,
              const float* __restrict__ varp, const float* __restrict__ lsp,
              float* __restrict__ out)
{
    const int tid  = threadIdx.x;
    const int nloc = tid & 63;
    const int wave = __builtin_amdgcn_readfirstlane(tid >> 6);
    const int s    = blockIdx.y;
    const int n    = blockIdx.x * 64 + nloc;
    const float variance = varp[0];
    const float inv_ls   = 1.0f / lsp[0];
    const float scale = sqrtf(2.0f * variance / (float)kF);
    float xa[kD];
    {
        const float4 x0 = *reinterpret_cast<const float4*>(X + n * kD);
        const float4 x1 = *reinterpret_cast<const float4*>(X + n * kD + 4);
        const float m = inv_ls * kInv2Pi;
        xa[0]=x0.x*m; xa[1]=x0.y*m; xa[2]=x0.z*m; xa[3]=x0.w*m;
        xa[4]=x1.x*m; xa[5]=x1.y*m; xa[6]=x1.z*m; xa[7]=x1.w*m;
    }
    const float* om  = omega + s * (kD * kF);
    const float* ph  = phase + s * kF;
    const float* fwp = fw    + s * kF;
    const int f0 = wave * 128;
    float acc0 = 0.f, acc1 = 0.f;
    for (int fb = f0; fb < f0 + 128; fb += 8) {
        float cv[8];
        #pragma unroll
        for (int j = 0; j < 8; ++j) {
            float t = ph[fb + j] * kInv2Pi;
            #pragma unroll
            for (int d = 0; d < kD; ++d) t = fmaf(xa[d], om[d * kF + fb + j], t);
            cv[j] = fast_cos2pi(fast_fract(t));
        }
        #pragma unroll
        for (int j = 0; j < 8; j += 2) {
            acc0 = fmaf(fwp[fb + j], cv[j], acc0);
            acc1 = fmaf(fwp[fb + j + 1], cv[j + 1], acc1);
        }
    }
    __shared__ float red[8][64];
    red[wave][nloc] = acc0 + acc1;
    __syncthreads();
    if (tid < 64) {
        float t = 0.f;
        #pragma unroll
        for (int k = 0; k < 8; ++k) t += red[k][tid];
        out[s * kN + blockIdx.x * 64 + tid] = scale * t;
    }
}

__global__ __launch_bounds__(1024, 8)
void update_fb(const float* __restrict__ X, const float* __restrict__ Z,
               const float* __restrict__ cw, const float* __restrict__ varp,
               const float* __restrict__ lsp, float* __restrict__ out)
{
    const int tid  = threadIdx.x;
    const int nloc = tid & 63;
    const int wave = __builtin_amdgcn_readfirstlane(tid >> 6);
    const int n    = blockIdx.x * 64 + nloc;
    const float variance = varp[0];
    const float inv_ls   = 1.0f / lsp[0];
    const float L = kLog2e * inv_ls * inv_ls;
    __shared__ float zt_lds[kR];
    __shared__ float red[16][64][kS + 1];
    float x[kD];
    {
        const float4 x0 = *reinterpret_cast<const float4*>(X + n * kD);
        const float4 x1 = *reinterpret_cast<const float4*>(X + n * kD + 4);
        x[0]=x0.x; x[1]=x0.y; x[2]=x0.z; x[3]=x0.w;
        x[4]=x1.x; x[5]=x1.y; x[6]=x1.z; x[7]=x1.w;
    }
    for (int r = tid; r < kR; r += 1024) {
        const float4 z0 = *reinterpret_cast<const float4*>(Z + r * kD);
        const float4 z1 = *reinterpret_cast<const float4*>(Z + r * kD + 4);
        float z2 = z0.x*z0.x + z0.y*z0.y + z0.z*z0.z + z0.w*z0.w
                 + z1.x*z1.x + z1.y*z1.y + z1.z*z1.z + z1.w*z1.w;
        zt_lds[r] = -0.5f * L * z2;
    }
    __syncthreads();
    float xb[kD]; float x2 = 0.f;
    #pragma unroll
    for (int d = 0; d < kD; ++d) { xb[d] = x[d] * L; x2 = fmaf(x[d], x[d], x2); }
    const float xt = -0.5f * L * x2;
    float accU[2][kS];
    #pragma unroll
    for (int j = 0; j < kS; ++j) { accU[0][j] = 0.f; accU[1][j] = 0.f; }
    const int r0 = wave * 128;
    #pragma unroll 4
    for (int rr = 0; rr < 128; ++rr) {
        const int r = r0 + rr;
        float e = xt + zt_lds[r];
        #pragma unroll
        for (int d = 0; d < kD; ++d) e = fmaf(xb[d], Z[r * kD + d], e);
        e = fminf(e, 0.f);
        const float K = fast_exp2(e);
        #pragma unroll
        for (int j = 0; j < kS; ++j)
            accU[rr & 1][j] = fmaf(K, cw[j * kR + r], accU[rr & 1][j]);
    }
    #pragma unroll
    for (int j = 0; j < kS; ++j) red[wave][nloc][j] = accU[0][j] + accU[1][j];
    __syncthreads();
    if (tid < 512) {
        const int n2 = tid & 63;
        const int jj = tid >> 6;
        float tot = 0.f;
        #pragma unroll
        for (int k = 0; k < 16; ++k) tot += red[k][n2][jj];
        const int idx = jj * kN + blockIdx.x * 64 + n2;
        out[idx] = fmaf(variance, tot, out[idx]);
    }
}

extern "C" void kernel_launch(void* const* d_in, const int* in_sizes, int n_in,
                              void* d_out, int out_size, void* d_ws, size_t ws_size,
                              hipStream_t stream) {
    const float* X  = (const float*)d_in[0];
    const float* Z  = (const float*)d_in[1];
    const float* om = (const float*)d_in[2];
    const float* ph = (const float*)d_in[3];
    const float* fw = (const float*)d_in[4];
    const float* cw = (const float*)d_in[5];
    const float* vp = (const float*)d_in[6];
    const float* lp = (const float*)d_in[7];
    float* out = (float*)d_out;

    if (ws_size >= kWsNeed) {
        uint4* wsP = (uint4*)d_ws;
        uint4* wsZ = wsP + (size_t)kWsPrior * 64;
        uint4* wsC = wsP + (size_t)(kWsPrior + kWsZ) * 64;
        hipLaunchKernelGGL(prep_kernel, dim3(208), dim3(256), 0, stream,
                           om, ph, Z, cw, lp, wsP, out);
        hipLaunchKernelGGL(fused_main, dim3(1536), dim3(256), 0, stream,
                           X, fw, vp, lp, wsP, wsZ, wsC, out);
    } else {
        hipLaunchKernelGGL(prior_fb, dim3(kN / 64, kS), dim3(512), 0, stream,
                           X, om, ph, fw, vp, lp, out);
        hipLaunchKernelGGL(update_fb, dim3(kN / 64), dim3(1024), 0, stream,
                           X, Z, cw, vp, lp, out);
    }
}

// Round 14
// 100.884 us; speedup vs baseline: 1.0472x; 1.0472x over previous
//
#include <hip/hip_runtime.h>
#include <math.h>

#ifndef __has_builtin
#define __has_builtin(x) 0
#endif

typedef __attribute__((ext_vector_type(8))) short bf16x8;
typedef __attribute__((ext_vector_type(4))) float f32x4;

__device__ __forceinline__ float fast_fract(float x) {
#if __has_builtin(__builtin_amdgcn_fractf)
    return __builtin_amdgcn_fractf(x);
#else
    return x - floorf(x);
#endif
}
__device__ __forceinline__ float fast_cos2pi(float x) {   // cos(2*pi*x), x in [0,1)
#if __has_builtin(__builtin_amdgcn_cosf)
    return __builtin_amdgcn_cosf(x);
#else
    return cosf(x * 6.28318530717958647692f);
#endif
}
__device__ __forceinline__ float fast_exp2(float x) {
#if __has_builtin(__builtin_amdgcn_exp2f)
    return __builtin_amdgcn_exp2f(x);
#else
    return exp2f(x);
#endif
}
__device__ __forceinline__ unsigned short f2bf(float f) { // RNE f32 -> bf16 bits
    unsigned u = __float_as_uint(f);
    return (unsigned short)((u + 0x7FFFu + ((u >> 16) & 1u)) >> 16);
}
__device__ __forceinline__ float bf2f(unsigned short b) {
    return __uint_as_float(((unsigned)b) << 16);
}
__device__ __forceinline__ unsigned packbf(float lo, float hi) { // 2 f32 -> u32 of 2 bf16
    return (unsigned)f2bf(lo) | ((unsigned)f2bf(hi) << 16);
}

constexpr int kN = 16384, kD = 8, kS = 8, kF = 1024, kR = 2048;
constexpr float kInv2Pi = 0.15915494309189535f;
constexpr float kLog2e  = 1.4426950408889634f;
// ws layout (tiles of 64 x uint4 = 1 KB):
//   [0,512)   prior B-frags (s,ft)
//   [512,640) update A1 z-frags (rt), rows = r
//   [640,704) update A2 cw^T frags (rb of 32 r), rows = s (8 valid)
constexpr int kWsPrior = 512, kWsZ = 128, kWsCw = 64;
constexpr int kWsTiles = kWsPrior + kWsZ + kWsCw;          // 704
constexpr size_t kWsNeed = (size_t)kWsTiles * 64 * 16;

// ===========================================================================
// PREP: build all MFMA fragments in d_ws (blocks 0..175) and ZERO out
// (blocks 176..207).  Fragment conventions verified (absmax 0.125, r6-r13).
// ===========================================================================
__global__ __launch_bounds__(256)
void prep_kernel(const float* __restrict__ omega, const float* __restrict__ phase,
                 const float* __restrict__ Z, const float* __restrict__ cw,
                 const float* __restrict__ lsp, uint4* __restrict__ ws,
                 float* __restrict__ out)
{
    if (blockIdx.x >= 176) {                       // zero out: 512 KB
        const int zid = (blockIdx.x - 176) * 256 + threadIdx.x;  // 0..8191
        float4* o4 = reinterpret_cast<float4*>(out);
        #pragma unroll
        for (int j = 0; j < 4; ++j)
            o4[zid * 4 + j] = (float4){0.f, 0.f, 0.f, 0.f};
        return;
    }
    const int job  = blockIdx.x * 256 + threadIdx.x;   // 0..45055
    const int lane = job & 63;
    const int tile = job >> 6;                          // 0..703
    const int g = lane >> 4, c = lane & 15;

    const float inv_ls = 1.0f / lsp[0];
    const float m_ang  = kInv2Pi * inv_ls;
    const float L      = kLog2e * inv_ls * inv_ls;

    unsigned short h[8];
    if (tile < kWsPrior) {
        const int s = tile >> 6, ft = tile & 63, f = ft * 16 + c;
        const float* om = omega + s * (kD * kF);
        const float* ph = phase + s * kF;
        #pragma unroll
        for (int j = 0; j < 8; ++j) {
            const int k = g * 8 + j;
            unsigned short v = 0;
            if (k < 16) {
                v = f2bf(om[(k & 7) * kF + f] * m_ang);
            } else if (k < 24) {
                const float w = om[(k - 16) * kF + f] * m_ang;
                v = f2bf(w - bf2f(f2bf(w)));
            } else if (k == 24) {
                v = f2bf(ph[f] * kInv2Pi);
            } else if (k == 25) {
                const float p = ph[f] * kInv2Pi;
                v = f2bf(p - bf2f(f2bf(p)));
            }
            h[j] = v;
        }
    } else if (tile < kWsPrior + kWsZ) {
        const int rt = tile - kWsPrior;
        const int r  = rt * 16 + c;                    // m = r (A-frag row)
        const float* zr = Z + r * kD;
        float zz = 0.f;
        #pragma unroll
        for (int d = 0; d < kD; ++d) zz = fmaf(zr[d], zr[d], zz);
        const float ztv = -0.5f * L * zz;
        #pragma unroll
        for (int j = 0; j < 8; ++j) {
            const int k = g * 8 + j;
            unsigned short v = 0;
            if (k < 8) {
                v = f2bf(L * zr[k]);
            } else if (k < 16) {
                v = f2bf(L * zr[k - 8]);
            } else if (k < 24) {
                const float w = L * zr[k - 16];
                v = f2bf(w - bf2f(f2bf(w)));
            } else if (k == 24) {
                v = f2bf(ztv);
            } else if (k == 25) {
                v = f2bf(ztv - bf2f(f2bf(ztv)));
            } else if (k < 28) {
                v = 0x3F80;                            // 1.0
            }
            h[j] = v;
        }
    } else {
        const int rb = tile - kWsPrior - kWsZ;         // 0..63
        const int r0 = rb * 32;
        #pragma unroll
        for (int j = 0; j < 8; ++j)
            h[j] = (c < 8) ? f2bf(cw[c * kR + r0 + g * 8 + j]) : (unsigned short)0;
    }
    uint4 w;
    w.x = (unsigned)h[0] | ((unsigned)h[1] << 16);
    w.y = (unsigned)h[2] | ((unsigned)h[3] << 16);
    w.z = (unsigned)h[4] | ((unsigned)h[5] << 16);
    w.w = (unsigned)h[6] | ((unsigned)h[7] << 16);
    ws[tile * 64 + lane] = w;
}

// Build x A/B fragment halves (g0/g2 = x_hi, g1 = x_lo).
__device__ __forceinline__ bf16x8 build_af_x(const float* __restrict__ X,
                                             int row, int g)
{
    float xv[kD];
    const float4 x0 = *reinterpret_cast<const float4*>(X + row * kD);
    const float4 x1 = *reinterpret_cast<const float4*>(X + row * kD + 4);
    xv[0]=x0.x; xv[1]=x0.y; xv[2]=x0.z; xv[3]=x0.w;
    xv[4]=x1.x; xv[5]=x1.y; xv[6]=x1.z; xv[7]=x1.w;
    bf16x8 af;
    if (g == 1) {
        #pragma unroll
        for (int j = 0; j < 8; ++j)
            af[j] = (short)f2bf(xv[j] - bf2f(f2bf(xv[j])));
    } else {
        #pragma unroll
        for (int j = 0; j < 8; ++j) af[j] = (short)f2bf(xv[j]);
    }
    return af;
}

// ===========================================================================
// FUSED MAIN v5: r13 structure with two fixes:
//  (a) PRIOR software-pipelined: MFMAs for pair i issue, then the trans
//      batch for pair i-1 runs (MFMA latency hidden under 128cy of cos).
//  (b) UPDATE transpose: vectorized uint2-write/uint4-read with compiler
//      memory fences on both sides (r11 speed, r13 ordering guarantee).
// grid 1536 x 256thr (4 waves) = 6 blocks/CU fully resident.
// Both atomicAdd into zeroed out.
// ===========================================================================
__global__ __launch_bounds__(256, 6)
void fused_main(const float* __restrict__ X, const float* __restrict__ fw,
                const float* __restrict__ varp, const float* __restrict__ lsp,
                const uint4* __restrict__ wsP, const uint4* __restrict__ wsZ,
                const uint4* __restrict__ wsC, float* __restrict__ out)
{
    __shared__ unsigned b2raw[4][256];                 // update transpose, 4 KB
    __shared__ f32x4 red[2][2][2][16];                 // update reduce, 2 KB
    const int tid  = threadIdx.x;
    const int lane = tid & 63;
    const int w    = __builtin_amdgcn_readfirstlane(tid >> 6);
    const int c = lane & 15, g = lane >> 4;
    const int bid = blockIdx.x;
    const int btype = bid % 3;                         // 0,1 prior; 2 update

    if (btype != 2) {
        // ---------------- PRIOR (software-pipelined) ----------------
        const int pb = (bid / 3) * 2 + btype;          // 0..1023
        const int s  = pb & 7;
        const int ng = pb >> 3;                        // 0..127
        const int n0 = ng * 128 + w * 32;

        bf16x8 af0, af1;
        if (g == 3) {
            #pragma unroll
            for (int j = 0; j < 8; ++j) { af0[j] = 0; af1[j] = 0; }
            af0[0] = (short)0x3F80; af0[1] = (short)0x3F80;
            af1[0] = (short)0x3F80; af1[1] = (short)0x3F80;
        } else {
            af0 = build_af_x(X, n0 + c, g);
            af1 = build_af_x(X, n0 + 16 + c, g);
        }

        const float scale = sqrtf(2.0f * varp[0] / (float)kF);
        const uint4* bp  = wsP + s * 4096 + lane;
        const float* fwp = fw + s * kF + c;

        float acc[2][4];
        #pragma unroll
        for (int t = 0; t < 2; ++t)
            #pragma unroll
            for (int r = 0; r < 4; ++r) acc[t][r] = 0.f;

        // prologue: pair 0 MFMAs in flight (pd), pair 1 frags loaded (b0,b1)
        uint4 b0 = bp[0], b1 = bp[64];
        f32x4 pd00, pd01, pd10, pd11;
        {
            const bf16x8 v0 = __builtin_bit_cast(bf16x8, b0);
            const bf16x8 v1 = __builtin_bit_cast(bf16x8, b1);
            pd00 = __builtin_amdgcn_mfma_f32_16x16x32_bf16(af0, v0, (f32x4){0.f,0.f,0.f,0.f}, 0, 0, 0);
            pd01 = __builtin_amdgcn_mfma_f32_16x16x32_bf16(af1, v0, (f32x4){0.f,0.f,0.f,0.f}, 0, 0, 0);
            pd10 = __builtin_amdgcn_mfma_f32_16x16x32_bf16(af0, v1, (f32x4){0.f,0.f,0.f,0.f}, 0, 0, 0);
            pd11 = __builtin_amdgcn_mfma_f32_16x16x32_bf16(af1, v1, (f32x4){0.f,0.f,0.f,0.f}, 0, 0, 0);
        }
        float cf0 = fwp[0], cf1 = fwp[16];
        b0 = bp[128]; b1 = bp[192];                    // frags for pair 1

        for (int it = 1; it < 32; ++it) {
            // prefetch pair it+1 frags
            const int nx = (it + 1 < 32) ? it + 1 : it;
            const uint4 p0 = bp[nx * 128];
            const uint4 p1 = bp[nx * 128 + 64];
            const float nf0 = fwp[it * 32];
            const float nf1 = fwp[it * 32 + 16];
            // issue MFMAs for pair it
            const bf16x8 v0 = __builtin_bit_cast(bf16x8, b0);
            const bf16x8 v1 = __builtin_bit_cast(bf16x8, b1);
            const f32x4 nd00 = __builtin_amdgcn_mfma_f32_16x16x32_bf16(af0, v0, (f32x4){0.f,0.f,0.f,0.f}, 0, 0, 0);
            const f32x4 nd01 = __builtin_amdgcn_mfma_f32_16x16x32_bf16(af1, v0, (f32x4){0.f,0.f,0.f,0.f}, 0, 0, 0);
            const f32x4 nd10 = __builtin_amdgcn_mfma_f32_16x16x32_bf16(af0, v1, (f32x4){0.f,0.f,0.f,0.f}, 0, 0, 0);
            const f32x4 nd11 = __builtin_amdgcn_mfma_f32_16x16x32_bf16(af1, v1, (f32x4){0.f,0.f,0.f,0.f}, 0, 0, 0);
            // trans batch for pair it-1 (pd) -- hides nd* MFMA latency
            #pragma unroll
            for (int r = 0; r < 4; ++r) {
                acc[0][r] = fmaf(cf0, fast_cos2pi(fast_fract(pd00[r])), acc[0][r]);
                acc[1][r] = fmaf(cf0, fast_cos2pi(fast_fract(pd01[r])), acc[1][r]);
                acc[0][r] = fmaf(cf1, fast_cos2pi(fast_fract(pd10[r])), acc[0][r]);
                acc[1][r] = fmaf(cf1, fast_cos2pi(fast_fract(pd11[r])), acc[1][r]);
            }
            pd00 = nd00; pd01 = nd01; pd10 = nd10; pd11 = nd11;
            cf0 = nf0; cf1 = nf1;
            b0 = p0; b1 = p1;
        }
        // epilogue: trans batch for pair 31
        #pragma unroll
        for (int r = 0; r < 4; ++r) {
            acc[0][r] = fmaf(cf0, fast_cos2pi(fast_fract(pd00[r])), acc[0][r]);
            acc[1][r] = fmaf(cf0, fast_cos2pi(fast_fract(pd01[r])), acc[1][r]);
            acc[0][r] = fmaf(cf1, fast_cos2pi(fast_fract(pd10[r])), acc[0][r]);
            acc[1][r] = fmaf(cf1, fast_cos2pi(fast_fract(pd11[r])), acc[1][r]);
        }

        #pragma unroll
        for (int m = 1; m <= 8; m <<= 1)
            #pragma unroll
            for (int t = 0; t < 2; ++t)
                #pragma unroll
                for (int r = 0; r < 4; ++r)
                    acc[t][r] += __shfl_xor(acc[t][r], m);

        if (c == 0) {
            #pragma unroll
            for (int t = 0; t < 2; ++t) {
                float* o = out + s * kN + n0 + t * 16 + g * 4;
                #pragma unroll
                for (int r = 0; r < 4; ++r) atomicAdd(o + r, scale * acc[t][r]);
            }
        }
    } else {
        // ---------------- UPDATE ----------------
        const int ub   = bid / 3;                      // 0..511
        const int tl   = w >> 1, half = w & 1;
        const int n0   = (ub * 2 + tl) * 16;

        const float inv_ls = 1.0f / lsp[0];
        const float L = kLog2e * inv_ls * inv_ls;

        bf16x8 bf1;
        {
            float xv[kD];
            const float4 x0 = *reinterpret_cast<const float4*>(X + (n0 + c) * kD);
            const float4 x1 = *reinterpret_cast<const float4*>(X + (n0 + c) * kD + 4);
            xv[0]=x0.x; xv[1]=x0.y; xv[2]=x0.z; xv[3]=x0.w;
            xv[4]=x1.x; xv[5]=x1.y; xv[6]=x1.z; xv[7]=x1.w;
            if (g == 3) {
                float xx = 0.f;
                #pragma unroll
                for (int d = 0; d < kD; ++d) xx = fmaf(xv[d], xv[d], xx);
                const float xt = -0.5f * L * xx;
                const unsigned short th = f2bf(xt);
                const unsigned short tlw = f2bf(xt - bf2f(th));
                #pragma unroll
                for (int j = 0; j < 8; ++j) bf1[j] = 0;
                bf1[0] = (short)0x3F80; bf1[1] = (short)0x3F80;
                bf1[2] = (short)th;     bf1[3] = (short)tlw;
            } else if (g == 1) {
                #pragma unroll
                for (int j = 0; j < 8; ++j)
                    bf1[j] = (short)f2bf(xv[j] - bf2f(f2bf(xv[j])));
            } else {
                #pragma unroll
                for (int j = 0; j < 8; ++j) bf1[j] = (short)f2bf(xv[j]);
            }
        }

        const int wbase = (g >> 1) * 64 + c * 4 + (g & 1) * 2;
        const int rbase = (g >> 1) * 128 + (g & 1) * 64 + c * 4;
        unsigned* bb = &b2raw[w][0];

        const uint4* zp = wsZ + lane;
        const uint4* cp = wsC + lane;
        const int rb0 = half * 32;

        f32x4 acc = {0.f, 0.f, 0.f, 0.f};
        uint4 za = zp[(rb0 * 2) * 64];
        uint4 zb = zp[(rb0 * 2 + 1) * 64];
        uint4 cf = cp[rb0 * 64];

        for (int i = 0; i < 32; ++i) {
            const int rb = rb0 + i;
            const int rbn = (i < 31) ? rb + 1 : rb;
            const uint4 zan = zp[(rbn * 2) * 64];      // depth-1 prefetch
            const uint4 zbn = zp[(rbn * 2 + 1) * 64];
            const uint4 cfn = cp[rbn * 64];

            const f32x4 e0 = __builtin_amdgcn_mfma_f32_16x16x32_bf16(
                __builtin_bit_cast(bf16x8, za), bf1, (f32x4){0.f,0.f,0.f,0.f}, 0, 0, 0);
            const f32x4 e1 = __builtin_amdgcn_mfma_f32_16x16x32_bf16(
                __builtin_bit_cast(bf16x8, zb), bf1, (f32x4){0.f,0.f,0.f,0.f}, 0, 0, 0);

            float K0[4], K1[4];
            #pragma unroll
            for (int r = 0; r < 4; ++r) {
                K0[r] = fast_exp2(fminf(e0[r], 0.f));
                K1[r] = fast_exp2(fminf(e1[r], 0.f));
            }
            // Vectorized in-wave transpose with explicit ordering fences:
            // uint2 writes -> fence -> uint4 read -> fence.  Program order
            // guaranteed (fixes r12 hazard) without scalarization (r13's
            // bank-conflict cost).
            uint2 w0; w0.x = packbf(K0[0], K0[1]); w0.y = packbf(K0[2], K0[3]);
            uint2 w1; w1.x = packbf(K1[0], K1[1]); w1.y = packbf(K1[2], K1[3]);
            *reinterpret_cast<uint2*>(&bb[wbase])       = w0;
            *reinterpret_cast<uint2*>(&bb[wbase + 128]) = w1;
            asm volatile("" ::: "memory");
            const uint4 b2w = *reinterpret_cast<const uint4*>(&bb[rbase]);
            asm volatile("" ::: "memory");

            acc = __builtin_amdgcn_mfma_f32_16x16x32_bf16(
                __builtin_bit_cast(bf16x8, cf), __builtin_bit_cast(bf16x8, b2w),
                acc, 0, 0, 0);

            za = zan; zb = zbn; cf = cfn;
        }

        if (g < 2) red[tl][half][g][c] = acc;
        __syncthreads();

        {
            const int tl2 = tid >> 7, s = (tid >> 4) & 7, n = tid & 15;
            const float sum = red[tl2][0][s >> 2][n][s & 3]
                            + red[tl2][1][s >> 2][n][s & 3];
            const int idx = s * kN + (ub * 2 + tl2) * 16 + n;
            atomicAdd(out + idx, varp[0] * sum);
        }
    }
}

// ===========================================================================
// Fallback (proven round-3 kernels) if ws_size is too small for fragments.
// ===========================================================================
__global__ __launch_bounds__(512, 8)
void prior_fb(const float* __restrict__ X, const float* __restrict__ omega,
              const float* __restrict__ phase, const float* __restrict__ fw,
              const float* __restrict__ varp, const float* __restrict__ lsp,
              float* __restrict__ out)
{
    const int tid  = threadIdx.x;
    const int nloc = tid & 63;
    const int wave = __builtin_amdgcn_readfirstlane(tid >> 6);
    const int s    = blockIdx.y;
    const int n    = blockIdx.x * 64 + nloc;
    const float variance = varp[0];
    const float inv_ls   = 1.0f / lsp[0];
    const float scale = sqrtf(2.0f * variance / (float)kF);
    float xa[kD];
    {
        const float4 x0 = *reinterpret_cast<const float4*>(X + n * kD);
        const float4 x1 = *reinterpret_cast<const float4*>(X + n * kD + 4);
        const float m = inv_ls * kInv2Pi;
        xa[0]=x0.x*m; xa[1]=x0.y*m; xa[2]=x0.z*m; xa[3]=x0.w*m;
        xa[4]=x1.x*m; xa[5]=x1.y*m; xa[6]=x1.z*m; xa[7]=x1.w*m;
    }
    const float* om  = omega + s * (kD * kF);
    const float* ph  = phase + s * kF;
    const float* fwp = fw    + s * kF;
    const int f0 = wave * 128;
    float acc0 = 0.f, acc1 = 0.f;
    for (int fb = f0; fb < f0 + 128; fb += 8) {
        float cv[8];
        #pragma unroll
        for (int j = 0; j < 8; ++j) {
            float t = ph[fb + j] * kInv2Pi;
            #pragma unroll
            for (int d = 0; d < kD; ++d) t = fmaf(xa[d], om[d * kF + fb + j], t);
            cv[j] = fast_cos2pi(fast_fract(t));
        }
        #pragma unroll
        for (int j = 0; j < 8; j += 2) {
            acc0 = fmaf(fwp[fb + j], cv[j], acc0);
            acc1 = fmaf(fwp[fb + j + 1], cv[j + 1], acc1);
        }
    }
    __shared__ float red[8][64];
    red[wave][nloc] = acc0 + acc1;
    __syncthreads();
    if (tid < 64) {
        float t = 0.f;
        #pragma unroll
        for (int k = 0; k < 8; ++k) t += red[k][tid];
        out[s * kN + blockIdx.x * 64 + tid] = scale * t;
    }
}

__global__ __launch_bounds__(1024, 8)
void update_fb(const float* __restrict__ X, const float* __restrict__ Z,
               const float* __restrict__ cw, const float* __restrict__ varp,
               const float* __restrict__ lsp, float* __restrict__ out)
{
    const int tid  = threadIdx.x;
    const int nloc = tid & 63;
    const int wave = __builtin_amdgcn_readfirstlane(tid >> 6);
    const int n    = blockIdx.x * 64 + nloc;
    const float variance = varp[0];
    const float inv_ls   = 1.0f / lsp[0];
    const float L = kLog2e * inv_ls * inv_ls;
    __shared__ float zt_lds[kR];
    __shared__ float red[16][64][kS + 1];
    float x[kD];
    {
        const float4 x0 = *reinterpret_cast<const float4*>(X + n * kD);
        const float4 x1 = *reinterpret_cast<const float4*>(X + n * kD + 4);
        x[0]=x0.x; x[1]=x0.y; x[2]=x0.z; x[3]=x0.w;
        x[4]=x1.x; x[5]=x1.y; x[6]=x1.z; x[7]=x1.w;
    }
    for (int r = tid; r < kR; r += 1024) {
        const float4 z0 = *reinterpret_cast<const float4*>(Z + r * kD);
        const float4 z1 = *reinterpret_cast<const float4*>(Z + r * kD + 4);
        float z2 = z0.x*z0.x + z0.y*z0.y + z0.z*z0.z + z0.w*z0.w
                 + z1.x*z1.x + z1.y*z1.y + z1.z*z1.z + z1.w*z1.w;
        zt_lds[r] = -0.5f * L * z2;
    }
    __syncthreads();
    float xb[kD]; float x2 = 0.f;
    #pragma unroll
    for (int d = 0; d < kD; ++d) { xb[d] = x[d] * L; x2 = fmaf(x[d], x[d], x2); }
    const float xt = -0.5f * L * x2;
    float accU[2][kS];
    #pragma unroll
    for (int j = 0; j < kS; ++j) { accU[0][j] = 0.f; accU[1][j] = 0.f; }
    const int r0 = wave * 128;
    #pragma unroll 4
    for (int rr = 0; rr < 128; ++rr) {
        const int r = r0 + rr;
        float e = xt + zt_lds[r];
        #pragma unroll
        for (int d = 0; d < kD; ++d) e = fmaf(xb[d], Z[r * kD + d], e);
        e = fminf(e, 0.f);
        const float K = fast_exp2(e);
        #pragma unroll
        for (int j = 0; j < kS; ++j)
            accU[rr & 1][j] = fmaf(K, cw[j * kR + r], accU[rr & 1][j]);
    }
    #pragma unroll
    for (int j = 0; j < kS; ++j) red[wave][nloc][j] = accU[0][j] + accU[1][j];
    __syncthreads();
    if (tid < 512) {
        const int n2 = tid & 63;
        const int jj = tid >> 6;
        float tot = 0.f;
        #pragma unroll
        for (int k = 0; k < 16; ++k) tot += red[k][n2][jj];
        const int idx = jj * kN + blockIdx.x * 64 + n2;
        out[idx] = fmaf(variance, tot, out[idx]);
    }
}

extern "C" void kernel_launch(void* const* d_in, const int* in_sizes, int n_in,
                              void* d_out, int out_size, void* d_ws, size_t ws_size,
                              hipStream_t stream) {
    const float* X  = (const float*)d_in[0];
    const float* Z  = (const float*)d_in[1];
    const float* om = (const float*)d_in[2];
    const float* ph = (const float*)d_in[3];
    const float* fw = (const float*)d_in[4];
    const float* cw = (const float*)d_in[5];
    const float* vp = (const float*)d_in[6];
    const float* lp = (const float*)d_in[7];
    float* out = (float*)d_out;

    if (ws_size >= kWsNeed) {
        uint4* wsP = (uint4*)d_ws;
        uint4* wsZ = wsP + (size_t)kWsPrior * 64;
        uint4* wsC = wsP + (size_t)(kWsPrior + kWsZ) * 64;
        hipLaunchKernelGGL(prep_kernel, dim3(208), dim3(256), 0, stream,
                           om, ph, Z, cw, lp, wsP, out);
        hipLaunchKernelGGL(fused_main, dim3(1536), dim3(256), 0, stream,
                           X, fw, vp, lp, wsP, wsZ, wsC, out);
    } else {
        hipLaunchKernelGGL(prior_fb, dim3(kN / 64, kS), dim3(512), 0, stream,
                           X, om, ph, fw, vp, lp, out);
        hipLaunchKernelGGL(update_fb, dim3(kN / 64), dim3(1024), 0, stream,
                           X, Z, cw, vp, lp, out);
    }
}

// Round 15
// 100.062 us; speedup vs baseline: 1.0558x; 1.0082x over previous
//
#include <hip/hip_runtime.h>
#include <math.h>

#ifndef __has_builtin
#define __has_builtin(x) 0
#endif

typedef __attribute__((ext_vector_type(8))) short bf16x8;
typedef __attribute__((ext_vector_type(4))) float f32x4;

__device__ __forceinline__ float fast_fract(float x) {
#if __has_builtin(__builtin_amdgcn_fractf)
    return __builtin_amdgcn_fractf(x);
#else
    return x - floorf(x);
#endif
}
__device__ __forceinline__ float fast_cos2pi(float x) {   // cos(2*pi*x), x in [0,1)
#if __has_builtin(__builtin_amdgcn_cosf)
    return __builtin_amdgcn_cosf(x);
#else
    return cosf(x * 6.28318530717958647692f);
#endif
}
__device__ __forceinline__ float fast_exp2(float x) {
#if __has_builtin(__builtin_amdgcn_exp2f)
    return __builtin_amdgcn_exp2f(x);
#else
    return exp2f(x);
#endif
}
__device__ __forceinline__ unsigned short f2bf(float f) { // RNE f32 -> bf16 bits
    unsigned u = __float_as_uint(f);
    return (unsigned short)((u + 0x7FFFu + ((u >> 16) & 1u)) >> 16);
}
__device__ __forceinline__ float bf2f(unsigned short b) {
    return __uint_as_float(((unsigned)b) << 16);
}
__device__ __forceinline__ unsigned packbf(float lo, float hi) { // 2 f32 -> u32 of 2 bf16
    return (unsigned)f2bf(lo) | ((unsigned)f2bf(hi) << 16);
}

constexpr int kN = 16384, kD = 8, kS = 8, kF = 1024, kR = 2048;
constexpr float kInv2Pi = 0.15915494309189535f;
constexpr float kLog2e  = 1.4426950408889634f;
// ws layout (tiles of 64 x uint4 = 1 KB):
//   [0,512)   prior B-frags (s,ft)
//   [512,640) update A1 z-frags (rt), rows = r
//   [640,704) update A2 cw^T frags (rb of 32 r), rows = s (8 valid)
constexpr int kWsPrior = 512, kWsZ = 128, kWsCw = 64;
constexpr int kWsTiles = kWsPrior + kWsZ + kWsCw;          // 704
constexpr size_t kWsNeed = (size_t)kWsTiles * 64 * 16;

// ===========================================================================
// PREP: build all MFMA fragments in d_ws (blocks 0..175) and ZERO out
// (blocks 176..207).  Fragment conventions verified (absmax 0.125, r6-r14).
// ===========================================================================
__global__ __launch_bounds__(256)
void prep_kernel(const float* __restrict__ omega, const float* __restrict__ phase,
                 const float* __restrict__ Z, const float* __restrict__ cw,
                 const float* __restrict__ lsp, uint4* __restrict__ ws,
                 float* __restrict__ out)
{
    if (blockIdx.x >= 176) {                       // zero out: 512 KB
        const int zid = (blockIdx.x - 176) * 256 + threadIdx.x;  // 0..8191
        float4* o4 = reinterpret_cast<float4*>(out);
        #pragma unroll
        for (int j = 0; j < 4; ++j)
            o4[zid * 4 + j] = (float4){0.f, 0.f, 0.f, 0.f};
        return;
    }
    const int job  = blockIdx.x * 256 + threadIdx.x;   // 0..45055
    const int lane = job & 63;
    const int tile = job >> 6;                          // 0..703
    const int g = lane >> 4, c = lane & 15;

    const float inv_ls = 1.0f / lsp[0];
    const float m_ang  = kInv2Pi * inv_ls;
    const float L      = kLog2e * inv_ls * inv_ls;

    unsigned short h[8];
    if (tile < kWsPrior) {
        const int s = tile >> 6, ft = tile & 63, f = ft * 16 + c;
        const float* om = omega + s * (kD * kF);
        const float* ph = phase + s * kF;
        #pragma unroll
        for (int j = 0; j < 8; ++j) {
            const int k = g * 8 + j;
            unsigned short v = 0;
            if (k < 16) {
                v = f2bf(om[(k & 7) * kF + f] * m_ang);
            } else if (k < 24) {
                const float w = om[(k - 16) * kF + f] * m_ang;
                v = f2bf(w - bf2f(f2bf(w)));
            } else if (k == 24) {
                v = f2bf(ph[f] * kInv2Pi);
            } else if (k == 25) {
                const float p = ph[f] * kInv2Pi;
                v = f2bf(p - bf2f(f2bf(p)));
            }
            h[j] = v;
        }
    } else if (tile < kWsPrior + kWsZ) {
        const int rt = tile - kWsPrior;
        const int r  = rt * 16 + c;                    // m = r (A-frag row)
        const float* zr = Z + r * kD;
        float zz = 0.f;
        #pragma unroll
        for (int d = 0; d < kD; ++d) zz = fmaf(zr[d], zr[d], zz);
        const float ztv = -0.5f * L * zz;
        #pragma unroll
        for (int j = 0; j < 8; ++j) {
            const int k = g * 8 + j;
            unsigned short v = 0;
            if (k < 8) {
                v = f2bf(L * zr[k]);
            } else if (k < 16) {
                v = f2bf(L * zr[k - 8]);
            } else if (k < 24) {
                const float w = L * zr[k - 16];
                v = f2bf(w - bf2f(f2bf(w)));
            } else if (k == 24) {
                v = f2bf(ztv);
            } else if (k == 25) {
                v = f2bf(ztv - bf2f(f2bf(ztv)));
            } else if (k < 28) {
                v = 0x3F80;                            // 1.0
            }
            h[j] = v;
        }
    } else {
        const int rb = tile - kWsPrior - kWsZ;         // 0..63
        const int r0 = rb * 32;
        #pragma unroll
        for (int j = 0; j < 8; ++j)
            h[j] = (c < 8) ? f2bf(cw[c * kR + r0 + g * 8 + j]) : (unsigned short)0;
    }
    uint4 w;
    w.x = (unsigned)h[0] | ((unsigned)h[1] << 16);
    w.y = (unsigned)h[2] | ((unsigned)h[3] << 16);
    w.z = (unsigned)h[4] | ((unsigned)h[5] << 16);
    w.w = (unsigned)h[6] | ((unsigned)h[7] << 16);
    ws[tile * 64 + lane] = w;
}

// Build x A/B fragment halves (g0/g2 = x_hi, g1 = x_lo).
__device__ __forceinline__ bf16x8 build_af_x(const float* __restrict__ X,
                                             int row, int g)
{
    float xv[kD];
    const float4 x0 = *reinterpret_cast<const float4*>(X + row * kD);
    const float4 x1 = *reinterpret_cast<const float4*>(X + row * kD + 4);
    xv[0]=x0.x; xv[1]=x0.y; xv[2]=x0.z; xv[3]=x0.w;
    xv[4]=x1.x; xv[5]=x1.y; xv[6]=x1.z; xv[7]=x1.w;
    bf16x8 af;
    if (g == 1) {
        #pragma unroll
        for (int j = 0; j < 8; ++j)
            af[j] = (short)f2bf(xv[j] - bf2f(f2bf(xv[j])));
    } else {
        #pragma unroll
        for (int j = 0; j < 8; ++j) af[j] = (short)f2bf(xv[j]);
    }
    return af;
}

// ===========================================================================
// FUSED MAIN v6: r14 (passed, 100.88us best) + DOUBLE-BUFFERED update
// transpose: K-frag of iteration i-1 is ds_read at the TOP of iteration i
// (issued ~280cy before its MFMA2 use at the bottom) -> the ~120cy LDS
// latency that was fully exposed in r7-r14's same-iteration round-trip is
// now hidden under MFMA1+exp.  Fence after the writes preserves the r12
// ordering fix.  Prior section byte-identical to r14.
// grid 1536 x 256thr (4 waves) = 6 blocks/CU fully resident.
// ===========================================================================
__global__ __launch_bounds__(256, 6)
void fused_main(const float* __restrict__ X, const float* __restrict__ fw,
                const float* __restrict__ varp, const float* __restrict__ lsp,
                const uint4* __restrict__ wsP, const uint4* __restrict__ wsZ,
                const uint4* __restrict__ wsC, float* __restrict__ out)
{
    __shared__ unsigned b2raw[4][512];                 // 2 transpose bufs/wave, 8 KB
    __shared__ f32x4 red[2][2][2][16];                 // update reduce, 2 KB
    const int tid  = threadIdx.x;
    const int lane = tid & 63;
    const int w    = __builtin_amdgcn_readfirstlane(tid >> 6);
    const int c = lane & 15, g = lane >> 4;
    const int bid = blockIdx.x;
    const int btype = bid % 3;                         // 0,1 prior; 2 update

    if (btype != 2) {
        // ---------------- PRIOR (software-pipelined, r14) ----------------
        const int pb = (bid / 3) * 2 + btype;          // 0..1023
        const int s  = pb & 7;
        const int ng = pb >> 3;                        // 0..127
        const int n0 = ng * 128 + w * 32;

        bf16x8 af0, af1;
        if (g == 3) {
            #pragma unroll
            for (int j = 0; j < 8; ++j) { af0[j] = 0; af1[j] = 0; }
            af0[0] = (short)0x3F80; af0[1] = (short)0x3F80;
            af1[0] = (short)0x3F80; af1[1] = (short)0x3F80;
        } else {
            af0 = build_af_x(X, n0 + c, g);
            af1 = build_af_x(X, n0 + 16 + c, g);
        }

        const float scale = sqrtf(2.0f * varp[0] / (float)kF);
        const uint4* bp  = wsP + s * 4096 + lane;
        const float* fwp = fw + s * kF + c;

        float acc[2][4];
        #pragma unroll
        for (int t = 0; t < 2; ++t)
            #pragma unroll
            for (int r = 0; r < 4; ++r) acc[t][r] = 0.f;

        uint4 b0 = bp[0], b1 = bp[64];
        f32x4 pd00, pd01, pd10, pd11;
        {
            const bf16x8 v0 = __builtin_bit_cast(bf16x8, b0);
            const bf16x8 v1 = __builtin_bit_cast(bf16x8, b1);
            pd00 = __builtin_amdgcn_mfma_f32_16x16x32_bf16(af0, v0, (f32x4){0.f,0.f,0.f,0.f}, 0, 0, 0);
            pd01 = __builtin_amdgcn_mfma_f32_16x16x32_bf16(af1, v0, (f32x4){0.f,0.f,0.f,0.f}, 0, 0, 0);
            pd10 = __builtin_amdgcn_mfma_f32_16x16x32_bf16(af0, v1, (f32x4){0.f,0.f,0.f,0.f}, 0, 0, 0);
            pd11 = __builtin_amdgcn_mfma_f32_16x16x32_bf16(af1, v1, (f32x4){0.f,0.f,0.f,0.f}, 0, 0, 0);
        }
        float cf0 = fwp[0], cf1 = fwp[16];
        b0 = bp[128]; b1 = bp[192];                    // frags for pair 1

        for (int it = 1; it < 32; ++it) {
            const int nx = (it + 1 < 32) ? it + 1 : it;
            const uint4 p0 = bp[nx * 128];
            const uint4 p1 = bp[nx * 128 + 64];
            const float nf0 = fwp[it * 32];
            const float nf1 = fwp[it * 32 + 16];
            const bf16x8 v0 = __builtin_bit_cast(bf16x8, b0);
            const bf16x8 v1 = __builtin_bit_cast(bf16x8, b1);
            const f32x4 nd00 = __builtin_amdgcn_mfma_f32_16x16x32_bf16(af0, v0, (f32x4){0.f,0.f,0.f,0.f}, 0, 0, 0);
            const f32x4 nd01 = __builtin_amdgcn_mfma_f32_16x16x32_bf16(af1, v0, (f32x4){0.f,0.f,0.f,0.f}, 0, 0, 0);
            const f32x4 nd10 = __builtin_amdgcn_mfma_f32_16x16x32_bf16(af0, v1, (f32x4){0.f,0.f,0.f,0.f}, 0, 0, 0);
            const f32x4 nd11 = __builtin_amdgcn_mfma_f32_16x16x32_bf16(af1, v1, (f32x4){0.f,0.f,0.f,0.f}, 0, 0, 0);
            #pragma unroll
            for (int r = 0; r < 4; ++r) {
                acc[0][r] = fmaf(cf0, fast_cos2pi(fast_fract(pd00[r])), acc[0][r]);
                acc[1][r] = fmaf(cf0, fast_cos2pi(fast_fract(pd01[r])), acc[1][r]);
                acc[0][r] = fmaf(cf1, fast_cos2pi(fast_fract(pd10[r])), acc[0][r]);
                acc[1][r] = fmaf(cf1, fast_cos2pi(fast_fract(pd11[r])), acc[1][r]);
            }
            pd00 = nd00; pd01 = nd01; pd10 = nd10; pd11 = nd11;
            cf0 = nf0; cf1 = nf1;
            b0 = p0; b1 = p1;
        }
        #pragma unroll
        for (int r = 0; r < 4; ++r) {
            acc[0][r] = fmaf(cf0, fast_cos2pi(fast_fract(pd00[r])), acc[0][r]);
            acc[1][r] = fmaf(cf0, fast_cos2pi(fast_fract(pd01[r])), acc[1][r]);
            acc[0][r] = fmaf(cf1, fast_cos2pi(fast_fract(pd10[r])), acc[0][r]);
            acc[1][r] = fmaf(cf1, fast_cos2pi(fast_fract(pd11[r])), acc[1][r]);
        }

        #pragma unroll
        for (int m = 1; m <= 8; m <<= 1)
            #pragma unroll
            for (int t = 0; t < 2; ++t)
                #pragma unroll
                for (int r = 0; r < 4; ++r)
                    acc[t][r] += __shfl_xor(acc[t][r], m);

        if (c == 0) {
            #pragma unroll
            for (int t = 0; t < 2; ++t) {
                float* o = out + s * kN + n0 + t * 16 + g * 4;
                #pragma unroll
                for (int r = 0; r < 4; ++r) atomicAdd(o + r, scale * acc[t][r]);
            }
        }
    } else {
        // ---------------- UPDATE (double-buffered transpose) ----------------
        const int ub   = bid / 3;                      // 0..511
        const int tl   = w >> 1, half = w & 1;
        const int n0   = (ub * 2 + tl) * 16;

        const float inv_ls = 1.0f / lsp[0];
        const float L = kLog2e * inv_ls * inv_ls;

        bf16x8 bf1;
        {
            float xv[kD];
            const float4 x0 = *reinterpret_cast<const float4*>(X + (n0 + c) * kD);
            const float4 x1 = *reinterpret_cast<const float4*>(X + (n0 + c) * kD + 4);
            xv[0]=x0.x; xv[1]=x0.y; xv[2]=x0.z; xv[3]=x0.w;
            xv[4]=x1.x; xv[5]=x1.y; xv[6]=x1.z; xv[7]=x1.w;
            if (g == 3) {
                float xx = 0.f;
                #pragma unroll
                for (int d = 0; d < kD; ++d) xx = fmaf(xv[d], xv[d], xx);
                const float xt = -0.5f * L * xx;
                const unsigned short th = f2bf(xt);
                const unsigned short tlw = f2bf(xt - bf2f(th));
                #pragma unroll
                for (int j = 0; j < 8; ++j) bf1[j] = 0;
                bf1[0] = (short)0x3F80; bf1[1] = (short)0x3F80;
                bf1[2] = (short)th;     bf1[3] = (short)tlw;
            } else if (g == 1) {
                #pragma unroll
                for (int j = 0; j < 8; ++j)
                    bf1[j] = (short)f2bf(xv[j] - bf2f(f2bf(xv[j])));
            } else {
                #pragma unroll
                for (int j = 0; j < 8; ++j) bf1[j] = (short)f2bf(xv[j]);
            }
        }

        const int wbase = (g >> 1) * 64 + c * 4 + (g & 1) * 2;
        const int rbase = (g >> 1) * 128 + (g & 1) * 64 + c * 4;
        unsigned* bb = &b2raw[w][0];                   // 2 bufs of 256 u32

        const uint4* zp = wsZ + lane;
        const uint4* cp = wsC + lane;
        const int rb0 = half * 32;

        f32x4 acc = {0.f, 0.f, 0.f, 0.f};
        uint4 za = zp[(rb0 * 2) * 64];
        uint4 zb = zp[(rb0 * 2 + 1) * 64];
        uint4 cf_cur = cp[rb0 * 64];
        uint4 cf_prev = cf_cur;

        // --- peeled iteration 0: MFMA1+exp, write buf0, no MFMA2 yet ---
        {
            const uint4 zan = zp[((rb0 + 1) * 2) * 64];
            const uint4 zbn = zp[((rb0 + 1) * 2 + 1) * 64];
            const uint4 cfn = cp[(rb0 + 1) * 64];
            const f32x4 e0 = __builtin_amdgcn_mfma_f32_16x16x32_bf16(
                __builtin_bit_cast(bf16x8, za), bf1, (f32x4){0.f,0.f,0.f,0.f}, 0, 0, 0);
            const f32x4 e1 = __builtin_amdgcn_mfma_f32_16x16x32_bf16(
                __builtin_bit_cast(bf16x8, zb), bf1, (f32x4){0.f,0.f,0.f,0.f}, 0, 0, 0);
            float K0[4], K1[4];
            #pragma unroll
            for (int r = 0; r < 4; ++r) {
                K0[r] = fast_exp2(fminf(e0[r], 0.f));
                K1[r] = fast_exp2(fminf(e1[r], 0.f));
            }
            uint2 w0; w0.x = packbf(K0[0], K0[1]); w0.y = packbf(K0[2], K0[3]);
            uint2 w1; w1.x = packbf(K1[0], K1[1]); w1.y = packbf(K1[2], K1[3]);
            *reinterpret_cast<uint2*>(&bb[wbase])       = w0;
            *reinterpret_cast<uint2*>(&bb[wbase + 128]) = w1;
            asm volatile("" ::: "memory");
            cf_prev = cf_cur; cf_cur = cfn; za = zan; zb = zbn;
        }

        // --- steady state i = 1..31: read buf[(i-1)&1] at TOP (latency
        //     hidden under MFMA1+exp), MFMA2 at BOTTOM ---
        for (int i = 1; i < 32; ++i) {
            const int rb = rb0 + i;
            const int rbn = (i < 31) ? rb + 1 : rb;
            const uint4 zan = zp[(rbn * 2) * 64];      // depth-1 prefetch
            const uint4 zbn = zp[(rbn * 2 + 1) * 64];
            const uint4 cfn = cp[rbn * 64];

            // early read of previous iteration's K-frag
            const uint4 kprev = *reinterpret_cast<const uint4*>(
                &bb[rbase + ((i - 1) & 1) * 256]);

            const f32x4 e0 = __builtin_amdgcn_mfma_f32_16x16x32_bf16(
                __builtin_bit_cast(bf16x8, za), bf1, (f32x4){0.f,0.f,0.f,0.f}, 0, 0, 0);
            const f32x4 e1 = __builtin_amdgcn_mfma_f32_16x16x32_bf16(
                __builtin_bit_cast(bf16x8, zb), bf1, (f32x4){0.f,0.f,0.f,0.f}, 0, 0, 0);

            float K0[4], K1[4];
            #pragma unroll
            for (int r = 0; r < 4; ++r) {
                K0[r] = fast_exp2(fminf(e0[r], 0.f));
                K1[r] = fast_exp2(fminf(e1[r], 0.f));
            }
            uint2 w0; w0.x = packbf(K0[0], K0[1]); w0.y = packbf(K0[2], K0[3]);
            uint2 w1; w1.x = packbf(K1[0], K1[1]); w1.y = packbf(K1[2], K1[3]);
            *reinterpret_cast<uint2*>(&bb[wbase + (i & 1) * 256])       = w0;
            *reinterpret_cast<uint2*>(&bb[wbase + 128 + (i & 1) * 256]) = w1;
            asm volatile("" ::: "memory");

            acc = __builtin_amdgcn_mfma_f32_16x16x32_bf16(
                __builtin_bit_cast(bf16x8, cf_prev), __builtin_bit_cast(bf16x8, kprev),
                acc, 0, 0, 0);

            cf_prev = cf_cur; cf_cur = cfn; za = zan; zb = zbn;
        }

        // --- epilogue: MFMA2 for iteration 31 ---
        {
            const uint4 kprev = *reinterpret_cast<const uint4*>(
                &bb[rbase + (31 & 1) * 256]);
            acc = __builtin_amdgcn_mfma_f32_16x16x32_bf16(
                __builtin_bit_cast(bf16x8, cf_prev), __builtin_bit_cast(bf16x8, kprev),
                acc, 0, 0, 0);
        }

        if (g < 2) red[tl][half][g][c] = acc;
        __syncthreads();

        {
            const int tl2 = tid >> 7, s = (tid >> 4) & 7, n = tid & 15;
            const float sum = red[tl2][0][s >> 2][n][s & 3]
                            + red[tl2][1][s >> 2][n][s & 3];
            const int idx = s * kN + (ub * 2 + tl2) * 16 + n;
            atomicAdd(out + idx, varp[0] * sum);
        }
    }
}

// ===========================================================================
// Fallback (proven round-3 kernels) if ws_size is too small for fragments.
// ===========================================================================
__global__ __launch_bounds__(512, 8)
void prior_fb(const float* __restrict__ X, const float* __restrict__ omega,
              const float* __restrict__ phase, const float* __restrict__ fw,
              const float* __restrict__ varp, const float* __restrict__ lsp,
              float* __restrict__ out)
{
    const int tid  = threadIdx.x;
    const int nloc = tid & 63;
    const int wave = __builtin_amdgcn_readfirstlane(tid >> 6);
    const int s    = blockIdx.y;
    const int n    = blockIdx.x * 64 + nloc;
    const float variance = varp[0];
    const float inv_ls   = 1.0f / lsp[0];
    const float scale = sqrtf(2.0f * variance / (float)kF);
    float xa[kD];
    {
        const float4 x0 = *reinterpret_cast<const float4*>(X + n * kD);
        const float4 x1 = *reinterpret_cast<const float4*>(X + n * kD + 4);
        const float m = inv_ls * kInv2Pi;
        xa[0]=x0.x*m; xa[1]=x0.y*m; xa[2]=x0.z*m; xa[3]=x0.w*m;
        xa[4]=x1.x*m; xa[5]=x1.y*m; xa[6]=x1.z*m; xa[7]=x1.w*m;
    }
    const float* om  = omega + s * (kD * kF);
    const float* ph  = phase + s * kF;
    const float* fwp = fw    + s * kF;
    const int f0 = wave * 128;
    float acc0 = 0.f, acc1 = 0.f;
    for (int fb = f0; fb < f0 + 128; fb += 8) {
        float cv[8];
        #pragma unroll
        for (int j = 0; j < 8; ++j) {
            float t = ph[fb + j] * kInv2Pi;
            #pragma unroll
            for (int d = 0; d < kD; ++d) t = fmaf(xa[d], om[d * kF + fb + j], t);
            cv[j] = fast_cos2pi(fast_fract(t));
        }
        #pragma unroll
        for (int j = 0; j < 8; j += 2) {
            acc0 = fmaf(fwp[fb + j], cv[j], acc0);
            acc1 = fmaf(fwp[fb + j + 1], cv[j + 1], acc1);
        }
    }
    __shared__ float red[8][64];
    red[wave][nloc] = acc0 + acc1;
    __syncthreads();
    if (tid < 64) {
        float t = 0.f;
        #pragma unroll
        for (int k = 0; k < 8; ++k) t += red[k][tid];
        out[s * kN + blockIdx.x * 64 + tid] = scale * t;
    }
}

__global__ __launch_bounds__(1024, 8)
void update_fb(const float* __restrict__ X, const float* __restrict__ Z,
               const float* __restrict__ cw, const float* __restrict__ varp,
               const float* __restrict__ lsp, float* __restrict__ out)
{
    const int tid  = threadIdx.x;
    const int nloc = tid & 63;
    const int wave = __builtin_amdgcn_readfirstlane(tid >> 6);
    const int n    = blockIdx.x * 64 + nloc;
    const float variance = varp[0];
    const float inv_ls   = 1.0f / lsp[0];
    const float L = kLog2e * inv_ls * inv_ls;
    __shared__ float zt_lds[kR];
    __shared__ float red[16][64][kS + 1];
    float x[kD];
    {
        const float4 x0 = *reinterpret_cast<const float4*>(X + n * kD);
        const float4 x1 = *reinterpret_cast<const float4*>(X + n * kD + 4);
        x[0]=x0.x; x[1]=x0.y; x[2]=x0.z; x[3]=x0.w;
        x[4]=x1.x; x[5]=x1.y; x[6]=x1.z; x[7]=x1.w;
    }
    for (int r = tid; r < kR; r += 1024) {
        const float4 z0 = *reinterpret_cast<const float4*>(Z + r * kD);
        const float4 z1 = *reinterpret_cast<const float4*>(Z + r * kD + 4);
        float z2 = z0.x*z0.x + z0.y*z0.y + z0.z*z0.z + z0.w*z0.w
                 + z1.x*z1.x + z1.y*z1.y + z1.z*z1.z + z1.w*z1.w;
        zt_lds[r] = -0.5f * L * z2;
    }
    __syncthreads();
    float xb[kD]; float x2 = 0.f;
    #pragma unroll
    for (int d = 0; d < kD; ++d) { xb[d] = x[d] * L; x2 = fmaf(x[d], x[d], x2); }
    const float xt = -0.5f * L * x2;
    float accU[2][kS];
    #pragma unroll
    for (int j = 0; j < kS; ++j) { accU[0][j] = 0.f; accU[1][j] = 0.f; }
    const int r0 = wave * 128;
    #pragma unroll 4
    for (int rr = 0; rr < 128; ++rr) {
        const int r = r0 + rr;
        float e = xt + zt_lds[r];
        #pragma unroll
        for (int d = 0; d < kD; ++d) e = fmaf(xb[d], Z[r * kD + d], e);
        e = fminf(e, 0.f);
        const float K = fast_exp2(e);
        #pragma unroll
        for (int j = 0; j < kS; ++j)
            accU[rr & 1][j] = fmaf(K, cw[j * kR + r], accU[rr & 1][j]);
    }
    #pragma unroll
    for (int j = 0; j < kS; ++j) red[wave][nloc][j] = accU[0][j] + accU[1][j];
    __syncthreads();
    if (tid < 512) {
        const int n2 = tid & 63;
        const int jj = tid >> 6;
        float tot = 0.f;
        #pragma unroll
        for (int k = 0; k < 16; ++k) tot += red[k][n2][jj];
        const int idx = jj * kN + blockIdx.x * 64 + n2;
        out[idx] = fmaf(variance, tot, out[idx]);
    }
}

extern "C" void kernel_launch(void* const* d_in, const int* in_sizes, int n_in,
                              void* d_out, int out_size, void* d_ws, size_t ws_size,
                              hipStream_t stream) {
    const float* X  = (const float*)d_in[0];
    const float* Z  = (const float*)d_in[1];
    const float* om = (const float*)d_in[2];
    const float* ph = (const float*)d_in[3];
    const float* fw = (const float*)d_in[4];
    const float* cw = (const float*)d_in[5];
    const float* vp = (const float*)d_in[6];
    const float* lp = (const float*)d_in[7];
    float* out = (float*)d_out;

    if (ws_size >= kWsNeed) {
        uint4* wsP = (uint4*)d_ws;
        uint4* wsZ = wsP + (size_t)kWsPrior * 64;
        uint4* wsC = wsP + (size_t)(kWsPrior + kWsZ) * 64;
        hipLaunchKernelGGL(prep_kernel, dim3(208), dim3(256), 0, stream,
                           om, ph, Z, cw, lp, wsP, out);
        hipLaunchKernelGGL(fused_main, dim3(1536), dim3(256), 0, stream,
                           X, fw, vp, lp, wsP, wsZ, wsC, out);
    } else {
        hipLaunchKernelGGL(prior_fb, dim3(kN / 64, kS), dim3(512), 0, stream,
                           X, om, ph, fw, vp, lp, out);
        hipLaunchKernelGGL(update_fb, dim3(kN / 64), dim3(1024), 0, stream,
                           X, Z, cw, vp, lp, out);
    }
}